// Round 5
// baseline (136.612 us; speedup 1.0000x reference)
//
#include <hip/hip_runtime.h>

// QueryLayer fused: h = input@W; p_ij = exp(adj_ij * lrelu(s1_i + s2_j))  [fixed shift M=0 — exact
// softmax up to normalization, range-safe since att <= ~20]; out = elu((p@h)/rowsum(p)), x4 copies.
// k_h: h row dot-products fp32 -> hT bf16 (transposed for MFMA B-frags), s1, s2.
// k_f: flash-style fused kernel. adj streamed via global_load_lds double-buffered 16x256 tiles
//      (wave w copies one row linearly = perfectly coalesced 1KB/instr); waves split each tile's
//      j-range for exp+MFMA; register acc + LDS combine; writes final output. adj read once.

#define NN 4096
#define INF 256
#define OUTF 64
#define ALPHA 0.2f
#define JTILE 256
#define NTILES (NN / JTILE)   // 16
#define TPAD 260              // padded LDS row stride (floats)

typedef __bf16 bf16;
typedef __bf16 bf16x8 __attribute__((ext_vector_type(8)));
typedef float floatx4 __attribute__((ext_vector_type(4)));

typedef const __attribute__((address_space(1))) void GV;
typedef __attribute__((address_space(3))) void LV;
#define GLD16(g, l) __builtin_amdgcn_global_load_lds((GV*)(g), (LV*)(l), 16, 0, 0)

// ---------------- kernel H: h = input@W (fp32), hT bf16, s1, s2 ----------------
__global__ __launch_bounds__(256) void k_h(const float* __restrict__ input,
                                           const float* __restrict__ W,
                                           const float* __restrict__ a,
                                           bf16* __restrict__ hT,
                                           float* __restrict__ s1,
                                           float* __restrict__ s2) {
    const int wid  = threadIdx.x >> 6;
    const int lane = threadIdx.x & 63;       // f = lane (OUTF==64)
    const int row  = blockIdx.x * 4 + wid;
    const float* in_row = input + (size_t)row * INF;
    float acc = 0.f;
    #pragma unroll 8
    for (int k = 0; k < INF; ++k)
        acc = fmaf(in_row[k], W[k * OUTF + lane], acc);
    hT[(size_t)lane * NN + row] = (bf16)acc;
    float v1 = acc * a[lane];
    float v2 = acc * a[OUTF + lane];
    #pragma unroll
    for (int off = 32; off; off >>= 1) {
        v1 += __shfl_down(v1, off);
        v2 += __shfl_down(v2, off);
    }
    if (lane == 0) { s1[row] = v1; s2[row] = v2; }
}

// ---------------- kernel F: fused softmax(adj*e) @ h + elu ----------------------
// Block: 16 output rows, 512 threads = 8 waves. Per 16x256 LDS tile, wave w owns the
// 32-j slice [w*32,(w+1)*32) -> one MFMA K-step per nt. acc accumulates over 16 tiles.
// MFMA 16x16x32 layouts (validated): A lane(q,r)=A[r][q*8+jj]; B lane(q,r)=hT[nt*16+r][q*8+jj];
// D lane(q,r) reg = D[q*4+reg][r].
__global__ __launch_bounds__(512, 1) void k_f(const float* __restrict__ adj,
                                              const float* __restrict__ s1,
                                              const float* __restrict__ s2,
                                              const bf16* __restrict__ hT,
                                              float* __restrict__ out) {
    __shared__ __align__(16) float tile[2][16 * TPAD];   // 2 x 16.6 KB
    __shared__ float sacc[8][1024];                      // 32 KB
    __shared__ float slr[8][16];

    const int b    = blockIdx.x;
    const int tid  = threadIdx.x;
    const int w    = tid >> 6;
    const int lane = tid & 63;
    const int q = lane >> 4, r = lane & 15;
    const int i0 = b * 16;
    const float s1i = s1[i0 + r];

    floatx4 acc[4] = {{0,0,0,0},{0,0,0,0},{0,0,0,0},{0,0,0,0}};
    float lsum = 0.f;

    // stage tile t into buf: wave w linearly copies rows w and w+8 (1 KB each, coalesced)
    #define STAGE(buf, t)                                                              \
        do {                                                                           \
            const float* g0 = adj + (size_t)(i0 + w) * NN + (t) * JTILE + lane * 4;    \
            const float* g1 = adj + (size_t)(i0 + w + 8) * NN + (t) * JTILE + lane * 4;\
            GLD16(g0, &tile[buf][w * TPAD]);                                           \
            GLD16(g1, &tile[buf][(w + 8) * TPAD]);                                     \
        } while (0)

    STAGE(0, 0);
    for (int t = 0; t < NTILES; ++t) {
        const int buf = t & 1;
        __syncthreads();                     // tile t ready; everyone done with buf^1
        if (t + 1 < NTILES) STAGE(buf ^ 1, t + 1);

        const int jb = t * JTILE + w * 32 + q * 8;
        const float* ap = &tile[buf][r * TPAD + w * 32 + q * 8];
        const float4 a0  = *(const float4*)ap;
        const float4 a1  = *(const float4*)(ap + 4);
        const float4 sv0 = *(const float4*)(s2 + jb);
        const float4 sv1 = *(const float4*)(s2 + jb + 4);
        float p0, p1, p2, p3, p4, p5, p6, p7, e;
        e = s1i + sv0.x; e = (e > 0.f ? e : ALPHA * e) * a0.x; p0 = __expf(e);
        e = s1i + sv0.y; e = (e > 0.f ? e : ALPHA * e) * a0.y; p1 = __expf(e);
        e = s1i + sv0.z; e = (e > 0.f ? e : ALPHA * e) * a0.z; p2 = __expf(e);
        e = s1i + sv0.w; e = (e > 0.f ? e : ALPHA * e) * a0.w; p3 = __expf(e);
        e = s1i + sv1.x; e = (e > 0.f ? e : ALPHA * e) * a1.x; p4 = __expf(e);
        e = s1i + sv1.y; e = (e > 0.f ? e : ALPHA * e) * a1.y; p5 = __expf(e);
        e = s1i + sv1.z; e = (e > 0.f ? e : ALPHA * e) * a1.z; p6 = __expf(e);
        e = s1i + sv1.w; e = (e > 0.f ? e : ALPHA * e) * a1.w; p7 = __expf(e);
        lsum += ((p0 + p1) + (p2 + p3)) + ((p4 + p5) + (p6 + p7));
        bf16x8 af;
        af[0] = (bf16)p0; af[1] = (bf16)p1; af[2] = (bf16)p2; af[3] = (bf16)p3;
        af[4] = (bf16)p4; af[5] = (bf16)p5; af[6] = (bf16)p6; af[7] = (bf16)p7;
        #pragma unroll
        for (int nt = 0; nt < 4; ++nt) {
            const bf16x8 bf = *(const bf16x8*)(hT + (size_t)(nt * 16 + r) * NN + jb);
            acc[nt] = __builtin_amdgcn_mfma_f32_16x16x32_bf16(af, bf, acc[nt], 0, 0, 0);
        }
    }
    #undef STAGE

    // per-row denominator within wave: sum the 4 q-lanes holding row r
    lsum += __shfl_xor(lsum, 16);
    lsum += __shfl_xor(lsum, 32);

    #pragma unroll
    for (int nt = 0; nt < 4; ++nt)
        #pragma unroll
        for (int reg = 0; reg < 4; ++reg)
            sacc[w][(q * 4 + reg) * 64 + nt * 16 + r] = acc[nt][reg];
    if (q == 0) slr[w][r] = lsum;
    __syncthreads();

    #pragma unroll
    for (int k = 0; k < 2; ++k) {
        const int idx = tid + k * 512;       // 0..1023 over the 16x64 tile
        const int row = idx >> 6, f = idx & 63;
        float s = 0.f, l = 0.f;
        #pragma unroll
        for (int ww = 0; ww < 8; ++ww) { s += sacc[ww][idx]; l += slr[ww][row]; }
        float v = s / l;
        v = v > 0.f ? v : (__expf(v) - 1.f);
        const size_t o = (size_t)(i0 + row) * OUTF + f;
        #pragma unroll
        for (int rr = 0; rr < 4; ++rr) out[(size_t)rr * (NN * OUTF) + o] = v;
    }
}

extern "C" void kernel_launch(void* const* d_in, const int* in_sizes, int n_in,
                              void* d_out, int out_size, void* d_ws, size_t ws_size,
                              hipStream_t stream) {
    (void)in_sizes; (void)n_in; (void)out_size; (void)ws_size;
    const float* input = (const float*)d_in[0];
    const float* adj   = (const float*)d_in[1];
    const float* W     = (const float*)d_in[2];
    const float* a     = (const float*)d_in[3];
    float* out = (float*)d_out;

    char* ws = (char*)d_ws;
    bf16*  hT = (bf16*)ws;                      // 512 KB
    float* s1 = (float*)(ws + (512 << 10));     // 16 KB
    float* s2 = (float*)(ws + (528 << 10));     // 16 KB

    hipLaunchKernelGGL(k_h, dim3(NN / 4), dim3(256), 0, stream, input, W, a, hT, s1, s2);
    hipLaunchKernelGGL(k_f, dim3(NN / 16), dim3(512), 0, stream, adj, s1, s2, hT, out);
}